// Round 5
// baseline (195.208 us; speedup 1.0000x reference)
//
#include <hip/hip_runtime.h>
#include <stdint.h>

#define N_NODES 100000
#define N_EDGES 1600000
#define HIDDEN  64
#define SLOPE   0.01f
#define NBUCK   391     // ceil(N_NODES/256): coarse buckets of 256 dst nodes
#define ECHUNK  4096    // edges per partition/hist chunk
#define CAP     2048    // LDS staging cap per 64-node sub-bucket (mean 1024, sd 32)

// round-to-nearest-even fp32 -> bf16 (as ushort)
__device__ __forceinline__ unsigned short f2bf(float f) {
    uint32_t u = __float_as_uint(f);
    uint32_t r = u + 0x7FFFu + ((u >> 16) & 1u);
    return (unsigned short)(r >> 16);
}

// K1: per-node scores s_i/s_j + bf16 copy of x. Blocks < NBUCK additionally
//     histogram one ECHUNK of edge dsts into bcnt (bcnt pre-zeroed by
//     hipMemsetAsync on the stream — capture-safe).
__global__ void __launch_bounds__(256) k_scores_hist(const float* __restrict__ x,
                                                     const float* __restrict__ w_i,
                                                     const float* __restrict__ w_j,
                                                     const int* __restrict__ dsts,
                                                     float* __restrict__ s_i,
                                                     float* __restrict__ s_j,
                                                     unsigned short* __restrict__ xb,
                                                     int* __restrict__ bcnt) {
    __shared__ int h[NBUCK];
    int tid = threadIdx.x;
    int node = blockIdx.x * 4 + (tid >> 6);
    int lane = tid & 63;
    if (node < N_NODES) {
        float v = x[node * HIDDEN + lane];
        xb[node * HIDDEN + lane] = f2bf(v);
        float a = v * w_i[lane];
        float b = v * w_j[lane];
        for (int off = 32; off > 0; off >>= 1) {
            a += __shfl_xor(a, off, 64);
            b += __shfl_xor(b, off, 64);
        }
        if (lane == 0) { s_i[node] = a; s_j[node] = b; }
    }
    if (blockIdx.x < NBUCK) {
        for (int b = tid; b < NBUCK; b += 256) h[b] = 0;
        __syncthreads();
        int e0 = blockIdx.x * ECHUNK;
        int e1 = min(e0 + ECHUNK, N_EDGES);
        for (int e = e0 + tid; e < e1; e += 256)
            atomicAdd(&h[dsts[e] >> 8], 1);
        __syncthreads();
        for (int b = tid; b < NBUCK; b += 256)
            if (h[b]) atomicAdd(&bcnt[b], h[b]);
    }
}

// K2: exclusive scan of the 391 bucket counts (single block); init cursors
__global__ void __launch_bounds__(512) k_bscan(const int* __restrict__ bcnt,
                                               int* __restrict__ boffs,
                                               int* __restrict__ bcursor) {
    __shared__ int sh[512];
    int tid = threadIdx.x;
    int v = (tid < NBUCK) ? bcnt[tid] : 0;
    sh[tid] = v;
    __syncthreads();
    for (int off = 1; off < 512; off <<= 1) {
        int t = (tid >= off) ? sh[tid - off] : 0;
        __syncthreads();
        sh[tid] += t;
        __syncthreads();
    }
    if (tid < NBUCK) {
        int o = sh[tid] - v;
        boffs[tid] = o;
        bcursor[tid] = o;
    }
}

// K3: partition edges into coarse buckets with LDS write-combining:
//     records are sorted into LDS by bucket, then copied out as contiguous
//     per-bucket runs (1-2 write transactions per run instead of per-edge
//     scattered 4B stores).
__global__ void __launch_bounds__(256) k_partition(const int* __restrict__ srcs,
                                                   const int* __restrict__ dsts,
                                                   int* __restrict__ bcursor,
                                                   uint32_t* __restrict__ pairs) {
    __shared__ int lcnt[NBUCK], lbase[NBUCK], lloc[NBUCK], lrank[NBUCK];
    __shared__ int scanbuf[256];
    __shared__ uint32_t srec[ECHUNK];
    int tid = threadIdx.x;
    for (int b = tid; b < NBUCK; b += 256) { lcnt[b] = 0; lrank[b] = 0; }
    __syncthreads();
    int e0 = blockIdx.x * ECHUNK;
    int e1 = min(e0 + ECHUNK, N_EDGES);
    // pass 1: per-bucket counts
    for (int e = e0 + tid; e < e1; e += 256)
        atomicAdd(&lcnt[dsts[e] >> 8], 1);
    __syncthreads();
    // block-local exclusive scan (2 bins/thread) + global range reservation
    int b0 = 2 * tid, b1 = 2 * tid + 1;
    int c0 = (b0 < NBUCK) ? lcnt[b0] : 0;
    int c1 = (b1 < NBUCK) ? lcnt[b1] : 0;
    scanbuf[tid] = c0 + c1;
    __syncthreads();
    for (int off = 1; off < 256; off <<= 1) {
        int t = (tid >= off) ? scanbuf[tid - off] : 0;
        __syncthreads();
        scanbuf[tid] += t;
        __syncthreads();
    }
    int base = scanbuf[tid] - (c0 + c1);
    if (b0 < NBUCK) {
        lloc[b0] = base;
        lbase[b0] = c0 ? atomicAdd(&bcursor[b0], c0) : 0;
    }
    if (b1 < NBUCK) {
        lloc[b1] = base + c0;
        lbase[b1] = c1 ? atomicAdd(&bcursor[b1], c1) : 0;
    }
    __syncthreads();
    // pass 2: sort records into LDS by bucket
    for (int e = e0 + tid; e < e1; e += 256) {
        int src = srcs[e];
        int dst = dsts[e];
        int b = dst >> 8;
        int r = atomicAdd(&lrank[b], 1);
        srec[lloc[b] + r] = ((uint32_t)(dst & 255) << 24) | (uint32_t)src;
    }
    __syncthreads();
    // pass 3: contiguous copy-out, one bucket segment per wave iteration
    int wave = tid >> 6, lane = tid & 63;
    for (int b = wave; b < NBUCK; b += 4) {
        int c = lcnt[b];
        if (!c) continue;
        int lo = lloc[b], go = lbase[b];
        for (int j = lane; j < c; j += 64)
            pairs[go + j] = srec[lo + j];
    }
}

// bf16-pair unpack helpers (uint32 = dims {2h, 2h+1} of a row)
__device__ __forceinline__ float bflo(uint32_t d) { return __uint_as_float(d << 16); }
__device__ __forceinline__ float bfhi(uint32_t d) { return __uint_as_float(d & 0xFFFF0000u); }

// batch of L load instructions covering 2L edges: half-wave h handles edges
// i+2t+h; lane = (h, hl) loads uint32 = dims {2hl, 2hl+1} of its edge's row.
template <int L>
__device__ __forceinline__ void gat_batch(const uint64_t* pp, int i, int half, int hl,
                                          const uint32_t* __restrict__ xw,
                                          float& accL, float& accH, float& den) {
    uint64_t q[L];
    uint32_t d[L];
#pragma unroll
    for (int t = 0; t < L; ++t) q[t] = pp[i + 2 * t + half];
#pragma unroll
    for (int t = 0; t < L; ++t)
        d[t] = xw[((uint32_t)q[t] & 0xFFFFFFu) * 32 + hl];
#pragma unroll
    for (int t = 0; t < L; ++t) {
        float w = __uint_as_float((uint32_t)(q[t] >> 32));
        den += w;
        accL = fmaf(w, bflo(d[t]), accL);
        accH = fmaf(w, bfhi(d[t]), accH);
    }
}

// K4: one block per 64 nodes. Stage {w,src} per node into LDS (w computed
//     here from s_i+s_j), then per-wave per-node accumulation where each
//     load instruction gathers TWO edges' rows (half-wave per row, 2 dims
//     per lane) — 2x MLP, half the gather instructions vs R4.
__global__ void __launch_bounds__(256) k_bucket_agg(const uint32_t* __restrict__ xw,
                                                    const uint32_t* __restrict__ pairs,
                                                    const int* __restrict__ boffs,
                                                    const int* __restrict__ bcnt,
                                                    const float* __restrict__ s_i,
                                                    const float* __restrict__ s_j,
                                                    float* __restrict__ out) {
    __shared__ uint64_t spairs[CAP];
    __shared__ int scnt[64], soff[64], scnt2[64];
    __shared__ float s_si[64];
    __shared__ int sovf;
    int tid = threadIdx.x;
    int g = blockIdx.x;                   // 64 nodes per block
    int cb = g >> 2, sub = g & 3;
    int node0 = g * 64;
    const uint32_t* reg = pairs + boffs[cb];
    int rcnt = bcnt[cb];
    if (tid < 64) {
        scnt[tid] = 0; scnt2[tid] = 0;
        int node = node0 + tid;
        s_si[tid] = (node < N_NODES) ? s_i[node] : 0.f;
    }
    if (tid == 0) sovf = 0;
    __syncthreads();
    // pass A: per-node degree count for this sub-bucket
    for (int e = tid; e < rcnt; e += 256) {
        int dstl = (int)(reg[e] >> 24);
        if ((dstl >> 6) == sub) atomicAdd(&scnt[dstl & 63], 1);
    }
    __syncthreads();
    // exclusive scan of 64 counts (wave 0, shfl)
    if (tid < 64) {
        int v = scnt[tid], s = v;
        for (int o = 1; o < 64; o <<= 1) {
            int t = __shfl_up(s, o, 64);
            if (tid >= o) s += t;
        }
        soff[tid] = s - v;
        if (tid == 63 && s > CAP) sovf = 1;
    }
    __syncthreads();
    int ovf = sovf;
    if (!ovf) {
        // pass B: w = exp(leaky(s_i+s_j)); scatter {w,src} per node into LDS
        for (int e = tid; e < rcnt; e += 256) {
            uint32_t p = reg[e];
            int dstl = (int)(p >> 24);
            if ((dstl >> 6) == sub) {
                int n = dstl & 63;
                int src = (int)(p & 0xFFFFFFu);
                float sc = s_si[n] + s_j[src];
                sc = (sc > 0.f) ? sc : SLOPE * sc;
                float w = __expf(sc);
                int r = atomicAdd(&scnt2[n], 1);
                spairs[soff[n] + r] =
                    ((uint64_t)__float_as_uint(w) << 32) | (uint32_t)src;
            }
        }
    }
    __syncthreads();
    int wave = tid >> 6, lane = tid & 63;
    int half = lane >> 5, hl = lane & 31;
    for (int k = wave; k < 64; k += 4) {
        int node = node0 + k;
        if (node >= N_NODES) break;
        float accL = 0.f, accH = 0.f, den = 0.f;
        int c = scnt[k];
        if (!ovf) {
            const uint64_t* pp = spairs + soff[k];
            int i = 0;
            for (; i + 16 <= c; i += 16) gat_batch<8>(pp, i, half, hl, xw, accL, accH, den);
            if (i + 8 <= c) { gat_batch<4>(pp, i, half, hl, xw, accL, accH, den); i += 8; }
            if (i + 4 <= c) { gat_batch<2>(pp, i, half, hl, xw, accL, accH, den); i += 4; }
            if (i + 2 <= c) { gat_batch<1>(pp, i, half, hl, xw, accL, accH, den); i += 2; }
            if (i < c) {
                // single edge: both halves load the same row; half 1 contributes 0
                uint64_t q = pp[i];
                float w = half ? 0.f : __uint_as_float((uint32_t)(q >> 32));
                uint32_t d = xw[((uint32_t)q & 0xFFFFFFu) * 32 + hl];
                den += w;
                accL = fmaf(w, bflo(d), accL);
                accH = fmaf(w, bfhi(d), accH);
            }
        } else {
            // safe fallback (statistically unreachable): scan whole region
            int sn = (sub << 6) | k;
            for (int e = 0; e < rcnt; ++e) {
                uint32_t p = reg[e];
                if ((int)(p >> 24) == sn) {
                    int src = (int)(p & 0xFFFFFFu);
                    float sc = s_si[k] + s_j[src];
                    sc = (sc > 0.f) ? sc : SLOPE * sc;
                    float w = half ? 0.f : __expf(sc);
                    uint32_t d = xw[(uint32_t)src * 32 + hl];
                    den += w;
                    accL = fmaf(w, bflo(d), accL);
                    accH = fmaf(w, bfhi(d), accH);
                }
            }
        }
        // combine the two halves; lanes 0-31 hold dims {2hl, 2hl+1}
        accL += __shfl_xor(accL, 32, 64);
        accH += __shfl_xor(accH, 32, 64);
        den  += __shfl_xor(den, 32, 64);
        if (half == 0) {
            float rL = 0.f, rH = 0.f;
            if (c > 0) {
                float inv = 1.f / den;
                rL = fmaxf(accL * inv, 0.f);
                rH = fmaxf(accH * inv, 0.f);
            }
            ((float2*)(out + (size_t)node * HIDDEN))[hl] = make_float2(rL, rH);
        }
    }
}

extern "C" void kernel_launch(void* const* d_in, const int* in_sizes, int n_in,
                              void* d_out, int out_size, void* d_ws, size_t ws_size,
                              hipStream_t stream) {
    const float* x   = (const float*)d_in[0];
    const int*   ei  = (const int*)d_in[1];   // [2, E]: row0 = src (ej), row1 = dst (ei)
    const float* w_i = (const float*)d_in[2];
    const float* w_j = (const float*)d_in[3];
    float* out = (float*)d_out;

    char* p = (char*)d_ws;
    float*          s_i     = (float*)p;          p += (size_t)N_NODES * 4;
    float*          s_j     = (float*)p;          p += (size_t)N_NODES * 4;
    unsigned short* xb      = (unsigned short*)p; p += (size_t)N_NODES * HIDDEN * 2;
    int*            bcnt    = (int*)p;            p += 4096;
    int*            boffs   = (int*)p;            p += 4096;
    int*            bcursor = (int*)p;            p += 4096;
    uint32_t*       pairs   = (uint32_t*)p;       // E * 4 bytes

    const int* srcs = ei;             // edge_index[0]
    const int* dsts = ei + N_EDGES;   // edge_index[1]

    int nagg = (N_NODES + 63) / 64;   // 1563 aggregate blocks

    hipMemsetAsync(bcnt, 0, NBUCK * sizeof(int), stream);
    k_scores_hist<<<(N_NODES + 3) / 4, 256, 0, stream>>>(x, w_i, w_j, dsts, s_i, s_j, xb, bcnt);
    k_bscan      <<<1, 512, 0, stream>>>(bcnt, boffs, bcursor);
    k_partition  <<<(N_EDGES + ECHUNK - 1) / ECHUNK, 256, 0, stream>>>(srcs, dsts, bcursor, pairs);
    k_bucket_agg <<<nagg, 256, 0, stream>>>((const uint32_t*)xb, pairs, boffs, bcnt, s_i, s_j, out);
}